// Round 3
// baseline (1523.839 us; speedup 1.0000x reference)
//
#include <hip/hip_runtime.h>
#include <hip/hip_bf16.h>

// OldODEFunc: B=8192, S=268, H=1024, R=8, A=256, E=4, Z=8, P=4.
// R2: ONE persistent fused kernel for the whole chain. 256 blocks x 32 rows.
// h/u live in LDS (bf16, xor-swizzled); weights bf16 streamed L2->B-frags
// directly with double-buffered 1:1 load<->MFMA interleave. No h HBM traffic.

typedef unsigned short u16;
typedef __bf16 bf16x8 __attribute__((ext_vector_type(8)));
typedef float f32x4 __attribute__((ext_vector_type(4)));

__device__ __forceinline__ u16 f2b(float f) {
  union { float f; unsigned u; } v; v.f = f;
  unsigned r = v.u + 0x7FFFu + ((v.u >> 16) & 1u);   // RNE
  return (u16)(r >> 16);
}
__device__ __forceinline__ float b2f(u16 s) {
  union { unsigned u; float f; } v; v.u = ((unsigned)s) << 16;
  return v.f;
}
// tanh via hw exp2: |err| ~1e-6, far under bf16 epilogue rounding
__device__ __forceinline__ float th(float x) {
  x = fminf(fmaxf(x, -40.f), 40.f);
  float a = __builtin_amdgcn_exp2f(2.88539008177793f * x);  // e^(2x)
  return (a - 1.f) * __builtin_amdgcn_rcpf(a + 1.f);
}

// Wave-level GEMM: C(32 x NT*16) += A(32 x K, LDS swizzled) * W^T
// W is (N x K) row-major bf16 in global (L2-hot), read straight into B-frags.
// LDS element (row,k) at (row*ldc + ((k>>3) ^ (row&7)))*8 + (k&7), ldc=K/8 chunks.
// Double-buffered b-frags: 16 loads interleaved with 32 MFMAs per k-step.
template<int NT, int K>
__device__ __forceinline__ void wgemm(const u16* __restrict__ As, const int ldc,
                                      const u16* __restrict__ Wg,
                                      const int n0, const int lane,
                                      f32x4 (&acc)[2][NT])
{
  const int lrow = lane & 15, quad = lane >> 4;
  const int sw = lrow & 7;
  const u16* wb = Wg + (size_t)(n0 + lrow) * K + quad * 8;
  bf16x8 bb[2][NT];
#pragma unroll
  for (int nt = 0; nt < NT; nt++)
    bb[0][nt] = *(const bf16x8*)(wb + (size_t)nt * 16 * K);
#pragma unroll
  for (int ks = 0; ks < K / 32; ks++) {
    const int cur = ks & 1, nxt = cur ^ 1;
    const int c = ks * 4 + quad;
    bf16x8 a0 = *(const bf16x8*)&As[(lrow * ldc + (c ^ sw)) * 8];
    bf16x8 a1 = *(const bf16x8*)&As[((16 + lrow) * ldc + (c ^ sw)) * 8];
#pragma unroll
    for (int nt = 0; nt < NT; nt++) {
      if (ks + 1 < K / 32)
        bb[nxt][nt] = *(const bf16x8*)(wb + (size_t)nt * 16 * K + (ks + 1) * 32);
      acc[0][nt] = __builtin_amdgcn_mfma_f32_16x16x32_bf16(a0, bb[cur][nt], acc[0][nt], 0, 0, 0);
      acc[1][nt] = __builtin_amdgcn_mfma_f32_16x16x32_bf16(a1, bb[cur][nt], acc[1][nt], 0, 0, 0);
    }
  }
}

#define LDS_U16 (32*320 + 32*1024 + 32*1024)   // x + h + u = 151552 bytes

__global__ __launch_bounds__(256, 1)
void fused_chain(const float* __restrict__ state, const float* __restrict__ t,
                 const u16* __restrict__ w0, const float* __restrict__ b0,
                 const u16* __restrict__ rw1, const float* __restrict__ rb1,
                 const u16* __restrict__ rw2, const float* __restrict__ rb2,
                 const u16* __restrict__ wf, const float* __restrict__ bfv,
                 const u16* __restrict__ taA, const float* __restrict__ ta_in_b,
                 const u16* __restrict__ taB, const float* __restrict__ ta_out_b,
                 const float* __restrict__ lp_in_w, const float* __restrict__ lp_in_b,
                 const float* __restrict__ lp_out_w, const float* __restrict__ lp_out_b,
                 const float* __restrict__ loc_proj_w, const float* __restrict__ loc_proj_b,
                 const float* __restrict__ loc_back_w, const float* __restrict__ loc_back_b,
                 float* __restrict__ out)
{
  extern __shared__ __align__(16) u16 sm[];
  u16* Xs = sm;                       // 32 x 320 bf16, ldc 40
  u16* Hs = sm + 32 * 320;            // 32 x 1024 bf16, ldc 128
  u16* Us = Hs + 32 * 1024;           // 32 x 1024 bf16, ldc 128 (v2: first 16KB; eh f32 at +16KB)
  float* ehf = (float*)(Us + 8192);   // 32 x 256 f32

  const int tid = threadIdx.x, lane = tid & 63, wave = tid >> 6;
  const int lrow = lane & 15, quad = lane >> 4;
  const int r0 = blockIdx.x << 5;     // 32 rows per block

  // ---- stage x = [state | sin | cos | pad] -> bf16 LDS (swizzled) ----
  const float ang = t[0] * 0.2617993877991494f;  // 2*pi/24
  const float sv = sinf(ang), cv = cosf(ang);
  for (int idx = tid; idx < 32 * 320; idx += 256) {
    const int r = idx / 320, c = idx - r * 320;
    float v;
    if (c < 268)      v = state[(size_t)(r0 + r) * 268 + c];
    else if (c == 268) v = sv;
    else if (c == 269) v = cv;
    else               v = 0.f;
    Xs[(r * 40 + ((c >> 3) ^ (r & 7))) * 8 + (c & 7)] = f2b(v);
  }
  __syncthreads();

  const f32x4 z4 = {0.f, 0.f, 0.f, 0.f};

  // ---- layer 0: h = relu(x @ W0^T + b0), K=320(pad), N=1024 ----
  {
    f32x4 acc[2][16];
#pragma unroll
    for (int i = 0; i < 2; i++)
#pragma unroll
      for (int nt = 0; nt < 16; nt++) acc[i][nt] = z4;
    wgemm<16, 320>(Xs, 40, w0, wave * 256, lane, acc);
#pragma unroll
    for (int i = 0; i < 2; i++)
#pragma unroll
      for (int nt = 0; nt < 16; nt++) {
        const int col = wave * 256 + nt * 16 + lrow;
        const float bi = b0[col];
#pragma unroll
        for (int r = 0; r < 4; r++) {
          const int row = i * 16 + quad * 4 + r;
          float v = acc[i][nt][r] + bi;
          v = v > 0.f ? v : 0.f;
          Hs[(row * 128 + ((col >> 3) ^ (row & 7))) * 8 + (col & 7)] = f2b(v);
        }
      }
  }
  __syncthreads();

  // ---- 8 residual blocks: h = tanh(h + tanh(h@W1^T+b1)@W2^T + b2) ----
  for (int rr = 0; rr < 8; rr++) {
    {
      f32x4 acc[2][16];
#pragma unroll
      for (int i = 0; i < 2; i++)
#pragma unroll
        for (int nt = 0; nt < 16; nt++) acc[i][nt] = z4;
      wgemm<16, 1024>(Hs, 128, rw1 + ((size_t)rr << 20), wave * 256, lane, acc);
      const float* b1 = rb1 + (rr << 10);
#pragma unroll
      for (int i = 0; i < 2; i++)
#pragma unroll
        for (int nt = 0; nt < 16; nt++) {
          const int col = wave * 256 + nt * 16 + lrow;
          const float bi = b1[col];
#pragma unroll
          for (int r = 0; r < 4; r++) {
            const int row = i * 16 + quad * 4 + r;
            Us[(row * 128 + ((col >> 3) ^ (row & 7))) * 8 + (col & 7)] =
                f2b(th(acc[i][nt][r] + bi));
          }
        }
    }
    __syncthreads();
    {
      f32x4 acc[2][16];
#pragma unroll
      for (int i = 0; i < 2; i++)
#pragma unroll
        for (int nt = 0; nt < 16; nt++) acc[i][nt] = z4;
      wgemm<16, 1024>(Us, 128, rw2 + ((size_t)rr << 20), wave * 256, lane, acc);
      const float* b2 = rb2 + (rr << 10);
#pragma unroll
      for (int i = 0; i < 2; i++)
#pragma unroll
        for (int nt = 0; nt < 16; nt++) {
          const int col = wave * 256 + nt * 16 + lrow;
          const float bi = b2[col];
#pragma unroll
          for (int r = 0; r < 4; r++) {
            const int row = i * 16 + quad * 4 + r;
            const int hidx = (row * 128 + ((col >> 3) ^ (row & 7))) * 8 + (col & 7);
            Hs[hidx] = f2b(th(acc[i][nt][r] + bi + b2f(Hs[hidx])));
          }
        }
    }
    __syncthreads();
  }

  // ---- ta path: v2 = x[:, :256] @ taA^T + b ; eh = v2 @ taB^T + b ----
  {
    f32x4 acc[2][4];
#pragma unroll
    for (int i = 0; i < 2; i++)
#pragma unroll
      for (int nt = 0; nt < 4; nt++) acc[i][nt] = z4;
    wgemm<4, 256>(Xs, 40, taA, wave * 64, lane, acc);
#pragma unroll
    for (int i = 0; i < 2; i++)
#pragma unroll
      for (int nt = 0; nt < 4; nt++) {
        const int col = wave * 64 + nt * 16 + lrow;
        const float bi = ta_in_b[512 + col];
#pragma unroll
        for (int r = 0; r < 4; r++) {
          const int row = i * 16 + quad * 4 + r;
          Us[(row * 32 + ((col >> 3) ^ (row & 7))) * 8 + (col & 7)] =
              f2b(acc[i][nt][r] + bi);
        }
      }
  }
  __syncthreads();
  {
    f32x4 acc[2][4];
#pragma unroll
    for (int i = 0; i < 2; i++)
#pragma unroll
      for (int nt = 0; nt < 4; nt++) acc[i][nt] = z4;
    wgemm<4, 256>(Us, 32, taB, wave * 64, lane, acc);
#pragma unroll
    for (int i = 0; i < 2; i++)
#pragma unroll
      for (int nt = 0; nt < 4; nt++) {
        const int col = wave * 64 + nt * 16 + lrow;
        const float bi = ta_out_b[col];
#pragma unroll
        for (int r = 0; r < 4; r++) {
          const int row = i * 16 + quad * 4 + r;
          ehf[row * 256 + col] = acc[i][nt][r] + bi;
        }
      }
  }
  __syncthreads();

  // ---- head: core = h @ Wf^T + bf (N pad 320), fused delta for cols<256 ----
  {
    f32x4 acc[2][5];
#pragma unroll
    for (int i = 0; i < 2; i++)
#pragma unroll
      for (int nt = 0; nt < 5; nt++) acc[i][nt] = z4;
    wgemm<5, 1024>(Hs, 128, wf, wave * 80, lane, acc);
#pragma unroll
    for (int i = 0; i < 2; i++)
#pragma unroll
      for (int nt = 0; nt < 5; nt++) {
        const int col = wave * 80 + nt * 16 + lrow;
        if (col < 268) {
          const float bi = bfv[col];
#pragma unroll
          for (int r = 0; r < 4; r++) {
            const int row = i * 16 + quad * 4 + r;
            float core = acc[i][nt][r] + bi;
            float o;
            if (col < 256) {
              const float st = state[(size_t)(r0 + row) * 268 + col];
              o = core + 0.1f * (ehf[row * 256 + col] - st);
            } else {
              o = core;   // cols 256..263 get loc delta below; 264..267 zero delta
            }
            out[(size_t)(r0 + row) * 268 + col] = o;
          }
        }
      }
  }
  __syncthreads();

  // ---- loc chain (exact fp32), one thread per row ----
  if (tid < 32) {
    const int row = tid;
    const float* sp = state + (size_t)(r0 + row) * 268 + 256;
    float locp[4], vv[4], dd[4];
#pragma unroll
    for (int e = 0; e < 4; e++) {
      float s = loc_proj_b[e];
#pragma unroll
      for (int z = 0; z < 8; z++) s += loc_proj_w[e * 8 + z] * sp[z];
      locp[e] = s;
    }
#pragma unroll
    for (int e = 0; e < 4; e++) {
      float s = lp_in_b[8 + e];
#pragma unroll
      for (int j = 0; j < 4; j++) s += lp_in_w[(8 + e) * 4 + j] * locp[j];
      vv[e] = s;
    }
#pragma unroll
    for (int e = 0; e < 4; e++) {
      float s = lp_out_b[e];
#pragma unroll
      for (int j = 0; j < 4; j++) s += lp_out_w[e * 4 + j] * vv[j];
      dd[e] = s - locp[e];
    }
#pragma unroll
    for (int z = 0; z < 8; z++) {
      float s = loc_back_b[z];
#pragma unroll
      for (int e = 0; e < 4; e++) s += loc_back_w[z * 4 + e] * dd[e];
      out[(size_t)(r0 + row) * 268 + 256 + z] += 0.1f * s;
    }
  }
}

// ---- prep: fp32 -> bf16 weight conversion ----
__global__ void conv_bulk(const float* __restrict__ w1, const float* __restrict__ w2,
                          u16* __restrict__ o1, u16* __restrict__ o2)
{
  const int n4 = (8 * 1024 * 1024) / 4;
  int i = blockIdx.x * 256 + threadIdx.x;
  const float* src; u16* dst;
  if (i < n4) { src = w1; dst = o1; }
  else        { i -= n4; if (i >= n4) return; src = w2; dst = o2; }
  float4 v = ((const float4*)src)[i];
  unsigned p0 = (unsigned)f2b(v.x) | ((unsigned)f2b(v.y) << 16);
  unsigned p1 = (unsigned)f2b(v.z) | ((unsigned)f2b(v.w) << 16);
  uint2 pk; pk.x = p0; pk.y = p1;
  ((uint2*)dst)[i] = pk;
}

// W0 pad(1024x320), Wf pad(320x1024), taA(256x256), taB(256x256)
__global__ void conv_misc(const float* __restrict__ W0, const float* __restrict__ Wf,
                          const float* __restrict__ ta_in_w, const float* __restrict__ ta_out_w,
                          u16* __restrict__ w0_bf, u16* __restrict__ wf_bf,
                          u16* __restrict__ taA, u16* __restrict__ taB)
{
  int i = blockIdx.x * 256 + threadIdx.x;
  const int nW0 = 1024 * 320;
  const int nWf = 320 * 1024;
  const int nTa = 256 * 256;
  if (i < nW0) {
    int o = i / 320, k = i - o * 320;
    w0_bf[i] = (k < 270) ? f2b(W0[o * 270 + k]) : (u16)0;
    return;
  }
  i -= nW0;
  if (i < nWf) {
    int n = i >> 10;
    wf_bf[i] = (n < 268) ? f2b(Wf[i]) : (u16)0;
    return;
  }
  i -= nWf;
  if (i < nTa) { taA[i] = f2b(ta_in_w[512 * 256 + i]); return; }
  i -= nTa;
  if (i < nTa) { taB[i] = f2b(ta_out_w[i]); }
}

extern "C" void kernel_launch(void* const* d_in, const int* in_sizes, int n_in,
                              void* d_out, int out_size, void* d_ws, size_t ws_size,
                              hipStream_t stream)
{
  const float* t          = (const float*)d_in[0];
  const float* state      = (const float*)d_in[1];
  const float* W0         = (const float*)d_in[2];
  const float* b0         = (const float*)d_in[3];
  const float* rW1        = (const float*)d_in[4];
  const float* rb1        = (const float*)d_in[5];
  const float* rW2        = (const float*)d_in[6];
  const float* rb2        = (const float*)d_in[7];
  const float* Wf         = (const float*)d_in[8];
  const float* bfv        = (const float*)d_in[9];
  const float* lp_in_w    = (const float*)d_in[10];
  const float* lp_in_b    = (const float*)d_in[11];
  const float* lp_out_w   = (const float*)d_in[12];
  const float* lp_out_b   = (const float*)d_in[13];
  const float* ta_in_w    = (const float*)d_in[14];
  const float* ta_in_b    = (const float*)d_in[15];
  const float* ta_out_w   = (const float*)d_in[16];
  const float* ta_out_b   = (const float*)d_in[17];
  const float* loc_proj_w = (const float*)d_in[18];
  const float* loc_proj_b = (const float*)d_in[19];
  const float* loc_back_w = (const float*)d_in[20];
  const float* loc_back_b = (const float*)d_in[21];
  float* out = (float*)d_out;

  char* ws = (char*)d_ws;
  auto alloc = [&](size_t bytes) { char* p = ws; ws += (bytes + 255) & ~(size_t)255; return p; };
  u16* rw1_bf = (u16*)alloc((size_t)8 * 1024 * 1024 * 2);
  u16* rw2_bf = (u16*)alloc((size_t)8 * 1024 * 1024 * 2);
  u16* w0_bf  = (u16*)alloc((size_t)1024 * 320 * 2);
  u16* wf_bf  = (u16*)alloc((size_t)320 * 1024 * 2);
  u16* taA_bf = (u16*)alloc((size_t)256 * 256 * 2);
  u16* taB_bf = (u16*)alloc((size_t)256 * 256 * 2);

  conv_bulk<<<16384, 256, 0, stream>>>(rW1, rW2, rw1_bf, rw2_bf);
  conv_misc<<<3072, 256, 0, stream>>>(W0, Wf, ta_in_w, ta_out_w,
                                      w0_bf, wf_bf, taA_bf, taB_bf);

  const int lds_bytes = LDS_U16 * 2;   // 151552
  hipFuncSetAttribute(reinterpret_cast<const void*>(fused_chain),
                      hipFuncAttributeMaxDynamicSharedMemorySize, lds_bytes);
  fused_chain<<<256, 256, lds_bytes, stream>>>(
      state, t, w0_bf, b0, rw1_bf, rb1, rw2_bf, rb2, wf_bf, bfv,
      taA_bf, ta_in_b, taB_bf, ta_out_b,
      lp_in_w, lp_in_b, lp_out_w, lp_out_b,
      loc_proj_w, loc_proj_b, loc_back_w, loc_back_b, out);
}

// Round 4
// 988.623 us; speedup vs baseline: 1.5414x; 1.5414x over previous
//
#include <hip/hip_runtime.h>
#include <hip/hip_bf16.h>

// OldODEFunc: B=8192, S=268, H=1024, R=8, A=256, E=4, Z=8, P=4.
// R4: layer-wise panel GEMM. 128Mx128N tile, A staged in 128x256 LDS panel
// phases (4 barriers/layer), B read direct global->VGPR double-buffered 1:1
// with MFMA. grid (N/128, M/128): XCD = n-index -> W slice stays L2-hot.

typedef unsigned short u16;
typedef __bf16 bf16x8 __attribute__((ext_vector_type(8)));
typedef float f32x4 __attribute__((ext_vector_type(4)));

__device__ __forceinline__ u16 f2b(float f) {
  union { float f; unsigned u; } v; v.f = f;
  unsigned r = v.u + 0x7FFFu + ((v.u >> 16) & 1u);   // RNE
  return (u16)(r >> 16);
}
__device__ __forceinline__ float b2f(u16 s) {
  union { unsigned u; float f; } v; v.u = ((unsigned)s) << 16;
  return v.f;
}

// async global->LDS, 16B per lane; lds dest = wave-uniform base + lane*16
__device__ __forceinline__ void g2l16(const u16* g, u16* l) {
  __builtin_amdgcn_global_load_lds(
      (__attribute__((address_space(1))) void*)g,
      (__attribute__((address_space(3))) void*)l, 16, 0, 0);
}

// ---------------- panel GEMM ----------------
// C(128M x 128N) = A(128 x K, row-major, lda) @ W(N x K)^T, K multiple of 256.
// A: LDS panel 128 x 256 per phase, xor-8 chunk swizzle (2-way alias = free).
// B: direct global->VGPR bf16x8 frags, double-buffered across substeps.
// 4 waves 2x2, each 64M x 64N (acc[4][4]).
// MODE 0: relu->bf16  1: tanh->bf16  2: tanh(+resid in-place)->bf16
// MODE 3: f32 out, cols<nreal  4: plain bf16
template<int MODE>
__global__ __launch_bounds__(256, 2)
void pgemm(const u16* __restrict__ A, const u16* __restrict__ W,
           const float* __restrict__ bias, const u16* __restrict__ resid,
           void* __restrict__ outp, int K, int lda, int nreal, int ldo)
{
  __shared__ __align__(16) u16 Ap[128 * 256];   // 64 KB
  const int tid  = threadIdx.x;
  const int wave = tid >> 6;
  const int lane = tid & 63;
  const int m0 = blockIdx.y << 7;
  const int n0 = blockIdx.x << 7;
  const int wr = wave >> 1, wc = wave & 1;
  const int lrow = lane & 15, quad = lane >> 4;
  const int sw = lrow & 7;
  // staging coords: 2 rows per g2l16 (64 lanes x 8 elems = 512 elems)
  const int rsub = lane >> 5;          // 0/1
  const int csub = lane & 31;          // chunk 0..31 within row

  const u16* Ag = A + (size_t)m0 * lda;
  const u16* wb = W + (size_t)(n0 + wc * 64 + lrow) * K + quad * 8;

  f32x4 acc[4][4];
#pragma unroll
  for (int i = 0; i < 4; i++)
#pragma unroll
    for (int nt = 0; nt < 4; nt++) { f32x4 z = {0.f,0.f,0.f,0.f}; acc[i][nt] = z; }

  // stage phase 0
#pragma unroll
  for (int g = 0; g < 16; g++) {
    const int row = wave * 32 + g * 2 + rsub;
    const int chunk = csub ^ (row & 7);
    g2l16(Ag + (size_t)row * lda + chunk * 8, &Ap[(wave * 32 + g * 2) * 256]);
  }
  __syncthreads();

  bf16x8 bb[2][4];
#pragma unroll
  for (int nt = 0; nt < 4; nt++)
    bb[0][nt] = *(const bf16x8*)(wb + (size_t)nt * 16 * K);

  const int phases = K >> 8;
  const int nsub   = K >> 5;
  for (int p = 0; p < phases; p++) {
    if (p) {
      __syncthreads();                 // prior phase reads done
      const int koff = p << 8;
#pragma unroll
      for (int g = 0; g < 16; g++) {
        const int row = wave * 32 + g * 2 + rsub;
        const int chunk = csub ^ (row & 7);
        g2l16(Ag + (size_t)row * lda + koff + chunk * 8,
              &Ap[(wave * 32 + g * 2) * 256]);
      }
      __syncthreads();                 // staging visible
    }
#pragma unroll
    for (int s = 0; s < 8; s++) {
      const int ks = p * 8 + s;
      const int cur = ks & 1;
      bf16x8 af[4];
#pragma unroll
      for (int i = 0; i < 4; i++) {
        const int ra = wr * 64 + i * 16 + lrow;
        af[i] = *(const bf16x8*)&Ap[(ra * 32 + ((s * 4 + quad) ^ sw)) * 8];
      }
      if (ks + 1 < nsub) {
        const int kn = (ks + 1) << 5;
#pragma unroll
        for (int nt = 0; nt < 4; nt++)
          bb[cur ^ 1][nt] = *(const bf16x8*)(wb + (size_t)nt * 16 * K + kn);
      }
#pragma unroll
      for (int i = 0; i < 4; i++)
#pragma unroll
        for (int nt = 0; nt < 4; nt++)
          acc[i][nt] = __builtin_amdgcn_mfma_f32_16x16x32_bf16(af[i], bb[cur][nt], acc[i][nt], 0, 0, 0);
    }
  }

  // tanh via hw exp2
  auto th = [](float x) {
    x = fminf(fmaxf(x, -40.f), 40.f);
    float a = __builtin_amdgcn_exp2f(2.88539008177793f * x);
    return (a - 1.f) * __builtin_amdgcn_rcpf(a + 1.f);
  };

  // epilogue: C/D layout col = lane&15, row = quad*4 + reg
#pragma unroll
  for (int i = 0; i < 4; i++) {
    const int rowb = m0 + wr * 64 + i * 16 + quad * 4;
#pragma unroll
    for (int nt = 0; nt < 4; nt++) {
      const int col = n0 + wc * 64 + nt * 16 + lrow;
      const float bi = (col < nreal) ? bias[col] : 0.f;
#pragma unroll
      for (int r = 0; r < 4; r++) {
        const int row = rowb + r;
        float v = acc[i][nt][r] + bi;
        if (MODE == 0) {
          v = v > 0.f ? v : 0.f;
          ((u16*)outp)[(size_t)row * ldo + col] = f2b(v);
        } else if (MODE == 1) {
          ((u16*)outp)[(size_t)row * ldo + col] = f2b(th(v));
        } else if (MODE == 2) {
          v += b2f(resid[(size_t)row * ldo + col]);
          ((u16*)outp)[(size_t)row * ldo + col] = f2b(th(v));
        } else if (MODE == 3) {
          if (col < nreal) ((float*)outp)[(size_t)row * ldo + col] = v;
        } else {
          ((u16*)outp)[(size_t)row * ldo + col] = f2b(v);
        }
      }
    }
  }
}

// ---------------- small GEMM (R2-proven, for ta path) ----------------
// 64M x 128N tile, BK=64, LDS-staged A and B, xor swizzle.
template<int MODE>
__global__ __launch_bounds__(256, 4)
void gemm_bt(const u16* __restrict__ A, const u16* __restrict__ B,
             const float* __restrict__ bias, const u16* __restrict__ resid,
             void* __restrict__ outp, int K, int lda, int nreal, int ldo)
{
  __shared__ __align__(16) u16 As[64 * 64];
  __shared__ __align__(16) u16 Bs[128 * 64];
  const int tid  = threadIdx.x;
  const int wave = tid >> 6;
  const int lane = tid & 63;
  const int m0 = blockIdx.y << 6;
  const int n0 = blockIdx.x << 7;
  const int wr = wave >> 1, wc = wave & 1;
  const int lrow = lane & 15, quad = lane >> 4;
  const int srow  = lane >> 3;
  const int sperm = ((lane & 7) ^ (srow & 7)) << 3;

  const u16* Ag0 = A + (size_t)(m0 + wave * 16 +  0 + srow) * lda + sperm;
  const u16* Ag1 = A + (size_t)(m0 + wave * 16 +  8 + srow) * lda + sperm;
  const u16* Bg0 = B + (size_t)(n0 + wave * 32 +  0 + srow) * K + sperm;
  const u16* Bg1 = B + (size_t)(n0 + wave * 32 +  8 + srow) * K + sperm;
  const u16* Bg2 = B + (size_t)(n0 + wave * 32 + 16 + srow) * K + sperm;
  const u16* Bg3 = B + (size_t)(n0 + wave * 32 + 24 + srow) * K + sperm;
  u16* Al0 = &As[(wave * 16 +  0) * 64];
  u16* Al1 = &As[(wave * 16 +  8) * 64];
  u16* Bl0 = &Bs[(wave * 32 +  0) * 64];
  u16* Bl1 = &Bs[(wave * 32 +  8) * 64];
  u16* Bl2 = &Bs[(wave * 32 + 16) * 64];
  u16* Bl3 = &Bs[(wave * 32 + 24) * 64];

  f32x4 acc[2][4];
#pragma unroll
  for (int i = 0; i < 2; i++)
#pragma unroll
    for (int j = 0; j < 4; j++) { f32x4 z = {0.f,0.f,0.f,0.f}; acc[i][j] = z; }

  const int swz = lrow & 7;

  for (int k0 = 0; k0 < K; k0 += 64) {
    if (k0) __syncthreads();
    g2l16(Ag0 + k0, Al0);
    g2l16(Ag1 + k0, Al1);
    g2l16(Bg0 + k0, Bl0);
    g2l16(Bg1 + k0, Bl1);
    g2l16(Bg2 + k0, Bl2);
    g2l16(Bg3 + k0, Bl3);
    __syncthreads();
#pragma unroll
    for (int s = 0; s < 2; s++) {
      const int c = (s * 4 + quad) ^ swz;
      bf16x8 af[2], bfr[4];
#pragma unroll
      for (int i = 0; i < 2; i++)
        af[i] = *(const bf16x8*)&As[((wr * 32 + i * 16 + lrow)) * 64 + c * 8];
#pragma unroll
      for (int j = 0; j < 4; j++)
        bfr[j] = *(const bf16x8*)&Bs[((wc * 64 + j * 16 + lrow)) * 64 + c * 8];
#pragma unroll
      for (int i = 0; i < 2; i++)
#pragma unroll
        for (int j = 0; j < 4; j++)
          acc[i][j] = __builtin_amdgcn_mfma_f32_16x16x32_bf16(af[i], bfr[j], acc[i][j], 0, 0, 0);
    }
  }

#pragma unroll
  for (int i = 0; i < 2; i++) {
    const int rowb = m0 + wr * 32 + i * 16 + quad * 4;
#pragma unroll
    for (int j = 0; j < 4; j++) {
      const int col = n0 + wc * 64 + j * 16 + lrow;
      const float bi = (col < nreal) ? bias[col] : 0.f;
#pragma unroll
      for (int r = 0; r < 4; r++) {
        const int row = rowb + r;
        float v = acc[i][j][r] + bi;
        ((u16*)outp)[(size_t)row * ldo + col] = f2b(v);  // MODE 4 only used
      }
    }
  }
}

// ---------------- prep ----------------
__global__ void conv_bulk(const float* __restrict__ w1, const float* __restrict__ w2,
                          u16* __restrict__ o1, u16* __restrict__ o2)
{
  const int n4 = (8 * 1024 * 1024) / 4;
  int i = blockIdx.x * 256 + threadIdx.x;
  const float* src; u16* dst;
  if (i < n4) { src = w1; dst = o1; }
  else        { i -= n4; if (i >= n4) return; src = w2; dst = o2; }
  float4 v = ((const float4*)src)[i];
  unsigned p0 = (unsigned)f2b(v.x) | ((unsigned)f2b(v.y) << 16);
  unsigned p1 = (unsigned)f2b(v.z) | ((unsigned)f2b(v.w) << 16);
  uint2 pk; pk.x = p0; pk.y = p1;
  ((uint2*)dst)[i] = pk;
}

// W0 pad(1024x512), Wf pad(384x1024), taA(256x256), taB(256x256), x_bf(8192x512)
__global__ void conv_misc(const float* __restrict__ W0, const float* __restrict__ Wf,
                          const float* __restrict__ ta_in_w, const float* __restrict__ ta_out_w,
                          const float* __restrict__ state, const float* __restrict__ t,
                          u16* __restrict__ w0_bf, u16* __restrict__ wf_bf,
                          u16* __restrict__ taA, u16* __restrict__ taB,
                          u16* __restrict__ x_bf)
{
  int i = blockIdx.x * 256 + threadIdx.x;
  const int nW0 = 1024 * 512;
  const int nWf = 384 * 1024;
  const int nTa = 256 * 256;
  const int nX  = 8192 * 512;
  if (i < nW0) {
    int o = i >> 9, k = i & 511;
    w0_bf[i] = (k < 270) ? f2b(W0[o * 270 + k]) : (u16)0;
    return;
  }
  i -= nW0;
  if (i < nWf) {
    int n = i >> 10;
    wf_bf[i] = (n < 268) ? f2b(Wf[i]) : (u16)0;
    return;
  }
  i -= nWf;
  if (i < nTa) { taA[i] = f2b(ta_in_w[512 * 256 + i]); return; }
  i -= nTa;
  if (i < nTa) { taB[i] = f2b(ta_out_w[i]); return; }
  i -= nTa;
  if (i < nX) {
    int r = i >> 9, c = i & 511;
    u16 v;
    if (c < 268) v = f2b(state[r * 268 + c]);
    else if (c == 268) { float ang = t[0] * 0.2617993877991494f; v = f2b(sinf(ang)); }
    else if (c == 269) { float ang = t[0] * 0.2617993877991494f; v = f2b(cosf(ang)); }
    else v = 0;
    x_bf[i] = v;
  }
}

// out += 0.1*delta
__global__ void add_delta(float* __restrict__ out, const u16* __restrict__ eh,
                          const float* __restrict__ state,
                          const float* __restrict__ lp_in_w, const float* __restrict__ lp_in_b,
                          const float* __restrict__ lp_out_w, const float* __restrict__ lp_out_b,
                          const float* __restrict__ loc_proj_w, const float* __restrict__ loc_proj_b,
                          const float* __restrict__ loc_back_w, const float* __restrict__ loc_back_b)
{
  const int idx = blockIdx.x * 256 + threadIdx.x;
  if (idx >= 8192 * 268) return;
  const int row = idx / 268;
  const int col = idx - row * 268;
  if (col < 256) {
    out[idx] += 0.1f * (b2f(eh[row * 256 + col]) - state[idx]);
  } else if (col < 264) {
    const float* srow = state + row * 268 + 256;
    float locp[4], vv[4], dd[4];
#pragma unroll
    for (int e = 0; e < 4; e++) {
      float s = loc_proj_b[e];
#pragma unroll
      for (int z = 0; z < 8; z++) s += loc_proj_w[e * 8 + z] * srow[z];
      locp[e] = s;
    }
#pragma unroll
    for (int e = 0; e < 4; e++) {
      float s = lp_in_b[8 + e];
#pragma unroll
      for (int j = 0; j < 4; j++) s += lp_in_w[(8 + e) * 4 + j] * locp[j];
      vv[e] = s;
    }
#pragma unroll
    for (int e = 0; e < 4; e++) {
      float s = lp_out_b[e];
#pragma unroll
      for (int j = 0; j < 4; j++) s += lp_out_w[e * 4 + j] * vv[j];
      dd[e] = s - locp[e];
    }
    const int z = col - 256;
    float s = loc_back_b[z];
#pragma unroll
    for (int e = 0; e < 4; e++) s += loc_back_w[z * 4 + e] * dd[e];
    out[idx] += 0.1f * s;
  }
}

extern "C" void kernel_launch(void* const* d_in, const int* in_sizes, int n_in,
                              void* d_out, int out_size, void* d_ws, size_t ws_size,
                              hipStream_t stream)
{
  const float* t          = (const float*)d_in[0];
  const float* state      = (const float*)d_in[1];
  const float* W0         = (const float*)d_in[2];
  const float* b0         = (const float*)d_in[3];
  const float* rW1        = (const float*)d_in[4];
  const float* rb1        = (const float*)d_in[5];
  const float* rW2        = (const float*)d_in[6];
  const float* rb2        = (const float*)d_in[7];
  const float* Wf         = (const float*)d_in[8];
  const float* bfv        = (const float*)d_in[9];
  const float* lp_in_w    = (const float*)d_in[10];
  const float* lp_in_b    = (const float*)d_in[11];
  const float* lp_out_w   = (const float*)d_in[12];
  const float* lp_out_b   = (const float*)d_in[13];
  const float* ta_in_w    = (const float*)d_in[14];
  const float* ta_in_b    = (const float*)d_in[15];
  const float* ta_out_w   = (const float*)d_in[16];
  const float* ta_out_b   = (const float*)d_in[17];
  const float* loc_proj_w = (const float*)d_in[18];
  const float* loc_proj_b = (const float*)d_in[19];
  const float* loc_back_w = (const float*)d_in[20];
  const float* loc_back_b = (const float*)d_in[21];
  float* out = (float*)d_out;

  char* ws = (char*)d_ws;
  auto alloc = [&](size_t bytes) { char* p = ws; ws += (bytes + 255) & ~(size_t)255; return p; };
  u16* rw1_bf = (u16*)alloc((size_t)8 * 1024 * 1024 * 2);
  u16* rw2_bf = (u16*)alloc((size_t)8 * 1024 * 1024 * 2);
  u16* w0_bf  = (u16*)alloc((size_t)1024 * 512 * 2);
  u16* wf_bf  = (u16*)alloc((size_t)384 * 1024 * 2);
  u16* taA_bf = (u16*)alloc((size_t)256 * 256 * 2);
  u16* taB_bf = (u16*)alloc((size_t)256 * 256 * 2);
  u16* x_bf   = (u16*)alloc((size_t)8192 * 512 * 2);
  u16* h_bf   = (u16*)alloc((size_t)8192 * 1024 * 2);
  u16* tmp_bf = (u16*)alloc((size_t)8192 * 1024 * 2);
  u16* v2_bf  = (u16*)alloc((size_t)8192 * 256 * 2);
  u16* eh_bf  = (u16*)alloc((size_t)8192 * 256 * 2);

  conv_bulk<<<16384, 256, 0, stream>>>(rW1, rW2, rw1_bf, rw2_bf);
  conv_misc<<<20480, 256, 0, stream>>>(W0, Wf, ta_in_w, ta_out_w, state, t,
                                       w0_bf, wf_bf, taA_bf, taB_bf, x_bf);

  // h = relu(x @ W0^T + b0)   K padded 270->512
  pgemm<0><<<dim3(8, 64), 256, 0, stream>>>(x_bf, w0_bf, b0, nullptr, h_bf, 512, 512, 1024, 1024);

  // 8 residual blocks
  for (int r = 0; r < 8; r++) {
    pgemm<1><<<dim3(8, 64), 256, 0, stream>>>(h_bf, rw1_bf + ((size_t)r << 20),
                                              rb1 + (r << 10), nullptr, tmp_bf, 1024, 1024, 1024, 1024);
    pgemm<2><<<dim3(8, 64), 256, 0, stream>>>(tmp_bf, rw2_bf + ((size_t)r << 20),
                                              rb2 + (r << 10), h_bf, h_bf, 1024, 1024, 1024, 1024);
  }

  // ta path (small): v2 = x[:, :256] @ taA^T + b ; eh = v2 @ taB^T + b
  gemm_bt<4><<<dim3(2, 128), 256, 0, stream>>>(x_bf, taA_bf, ta_in_b + 512, nullptr, v2_bf, 256, 512, 256, 256);
  gemm_bt<4><<<dim3(2, 128), 256, 0, stream>>>(v2_bf, taB_bf, ta_out_b, nullptr, eh_bf, 256, 256, 256, 256);

  // core = h @ Wf^T + bf -> f32 out (N padded 268->384)
  pgemm<3><<<dim3(3, 64), 256, 0, stream>>>(h_bf, wf_bf, bfv, nullptr, out, 1024, 1024, 268, 268);

  // out += 0.1*delta
  add_delta<<<8576, 256, 0, stream>>>(out, eh_bf, state,
                                      lp_in_w, lp_in_b, lp_out_w, lp_out_b,
                                      loc_proj_w, loc_proj_b, loc_back_w, loc_back_b);
}

// Round 5
// 697.503 us; speedup vs baseline: 2.1847x; 1.4174x over previous
//
#include <hip/hip_runtime.h>
#include <hip/hip_bf16.h>

// OldODEFunc: B=8192, S=268, H=1024, R=8, A=256, E=4, Z=8, P=4.
// R5: m97-style both-LDS-staged 128x128 GEMM with BK=128 phases.
// 512 blocks (2/CU cap from grid size) -> amortize barrier drains with big
// phases + 2-wave/SIMD interleave. K/LDA templated (static addressing).
// Grid (N/128, M/128): blockIdx.x = n-index -> per-XCD W slice L2-hot.

typedef unsigned short u16;
typedef __bf16 bf16x8 __attribute__((ext_vector_type(8)));
typedef float f32x4 __attribute__((ext_vector_type(4)));

__device__ __forceinline__ u16 f2b(float f) {
  union { float f; unsigned u; } v; v.f = f;
  unsigned r = v.u + 0x7FFFu + ((v.u >> 16) & 1u);   // RNE
  return (u16)(r >> 16);
}
__device__ __forceinline__ float b2f(u16 s) {
  union { unsigned u; float f; } v; v.u = ((unsigned)s) << 16;
  return v.f;
}

// async global->LDS, 16B per lane; lds dest = wave-uniform base + lane*16
__device__ __forceinline__ void g2l16(const u16* g, u16* l) {
  __builtin_amdgcn_global_load_lds(
      (__attribute__((address_space(1))) void*)g,
      (__attribute__((address_space(3))) void*)l, 16, 0, 0);
}

// ---------------- main GEMM ----------------
// C(128M x 128N) = A(128 x KK, row-major, LDA) @ W(N x KK)^T.
// LDS: As/Bs 128 x 128 bf16 (32 KB each), rows of 16 8-elem chunks,
// chunk swizzle: logical c stored at phys c ^ (row & 7).
// 4 waves 2x2, each 64x64 (acc[4][4]). Phase = BK 128: 16 g2l16/wave,
// one drain, 4 substeps x 16 MFMA.
// MODE 0: relu->bf16  1: tanh->bf16  2: tanh(+resid in-place)->bf16
// MODE 3: f32 out, cols<nreal
template<int MODE, int KK, int LDA>
__global__ __launch_bounds__(256, 2)
void pgemm(const u16* __restrict__ A, const u16* __restrict__ W,
           const float* __restrict__ bias, const u16* __restrict__ resid,
           void* __restrict__ outp, int nreal, int ldo)
{
  __shared__ __align__(16) u16 As[128 * 128];   // 32 KB
  __shared__ __align__(16) u16 Bs[128 * 128];   // 32 KB
  const int tid  = threadIdx.x;
  const int wave = tid >> 6;
  const int lane = tid & 63;
  const int m0 = blockIdx.y << 7;
  const int n0 = blockIdx.x << 7;
  const int wr = wave >> 1, wc = wave & 1;
  const int lrow = lane & 15, quad = lane >> 4;
  const int sw = lrow & 7;

  // staging: each inst covers 4 rows x 128 elems (64 lanes x 16B).
  const int srow4  = lane >> 4;        // row within 4-row group
  const int schunk = lane & 15;        // phys chunk within row
  // logical chunk to fetch so phys p holds logical p ^ (row&7):
  const int ce = (schunk ^ (srow4 & 7)) << 3;        // g even: row&7 = srow4
  const int co = (schunk ^ ((srow4 + 4) & 7)) << 3;  // g odd:  row&7 = srow4+4

  const u16* aE = A + (size_t)(m0 + wave * 32 + srow4) * LDA + ce;
  const u16* aO = A + (size_t)(m0 + wave * 32 + srow4) * LDA + co;
  const u16* bE = W + (size_t)(n0 + wave * 32 + srow4) * KK + ce;
  const u16* bO = W + (size_t)(n0 + wave * 32 + srow4) * KK + co;
  u16* AsW = &As[(wave * 32) * 128];
  u16* BsW = &Bs[(wave * 32) * 128];

  f32x4 acc[4][4];
#pragma unroll
  for (int i = 0; i < 4; i++)
#pragma unroll
    for (int j = 0; j < 4; j++) { f32x4 z = {0.f,0.f,0.f,0.f}; acc[i][j] = z; }

  for (int p = 0; p < KK / 128; p++) {
    if (p) __syncthreads();            // prior phase reads done
    const int ko = p << 7;
#pragma unroll
    for (int g = 0; g < 8; g++)
      g2l16(((g & 1) ? aO : aE) + g * 4 * LDA + ko, AsW + g * 4 * 128);
#pragma unroll
    for (int g = 0; g < 8; g++)
      g2l16(((g & 1) ? bO : bE) + g * 4 * KK + ko, BsW + g * 4 * 128);
    __syncthreads();                   // vmcnt(0) drain: staging visible
#pragma unroll
    for (int s = 0; s < 4; s++) {
      const int phys = (s * 4 + quad) ^ sw;
      bf16x8 af[4], bfr[4];
#pragma unroll
      for (int i = 0; i < 4; i++) {
        const int ra = wr * 64 + i * 16 + lrow;
        af[i] = *(const bf16x8*)&As[(ra * 16 + phys) * 8];
      }
#pragma unroll
      for (int j = 0; j < 4; j++) {
        const int rb = wc * 64 + j * 16 + lrow;
        bfr[j] = *(const bf16x8*)&Bs[(rb * 16 + phys) * 8];
      }
#pragma unroll
      for (int i = 0; i < 4; i++)
#pragma unroll
        for (int j = 0; j < 4; j++)
          acc[i][j] = __builtin_amdgcn_mfma_f32_16x16x32_bf16(af[i], bfr[j], acc[i][j], 0, 0, 0);
    }
  }

  auto th = [](float x) {
    x = fminf(fmaxf(x, -40.f), 40.f);
    float a = __builtin_amdgcn_exp2f(2.88539008177793f * x);
    return (a - 1.f) * __builtin_amdgcn_rcpf(a + 1.f);
  };

  // epilogue: C/D layout col = lane&15, row = quad*4 + reg
#pragma unroll
  for (int i = 0; i < 4; i++) {
    const int rowb = m0 + wr * 64 + i * 16 + quad * 4;
#pragma unroll
    for (int j = 0; j < 4; j++) {
      const int col = n0 + wc * 64 + j * 16 + lrow;
      const float bi = (col < nreal) ? bias[col] : 0.f;
#pragma unroll
      for (int r = 0; r < 4; r++) {
        const int row = rowb + r;
        float v = acc[i][j][r] + bi;
        if (MODE == 0) {
          v = v > 0.f ? v : 0.f;
          ((u16*)outp)[(size_t)row * ldo + col] = f2b(v);
        } else if (MODE == 1) {
          ((u16*)outp)[(size_t)row * ldo + col] = f2b(th(v));
        } else if (MODE == 2) {
          v += b2f(resid[(size_t)row * ldo + col]);
          ((u16*)outp)[(size_t)row * ldo + col] = f2b(th(v));
        } else if (MODE == 3) {
          if (col < nreal) ((float*)outp)[(size_t)row * ldo + col] = v;
        }
      }
    }
  }
}

// ---------------- small GEMM for ta path (R2-proven) ----------------
// 64M x 128N tile, BK=64, LDS-staged, xor swizzle, plain bf16 out.
__global__ __launch_bounds__(256, 4)
void gemm_bt(const u16* __restrict__ A, const u16* __restrict__ B,
             const float* __restrict__ bias, u16* __restrict__ outp,
             int K, int lda, int ldo)
{
  __shared__ __align__(16) u16 As[64 * 64];
  __shared__ __align__(16) u16 Bs[128 * 64];
  const int tid  = threadIdx.x;
  const int wave = tid >> 6;
  const int lane = tid & 63;
  const int m0 = blockIdx.y << 6;
  const int n0 = blockIdx.x << 7;
  const int wr = wave >> 1, wc = wave & 1;
  const int lrow = lane & 15, quad = lane >> 4;
  const int srow  = lane >> 3;
  const int sperm = ((lane & 7) ^ (srow & 7)) << 3;

  const u16* Ag0 = A + (size_t)(m0 + wave * 16 +  0 + srow) * lda + sperm;
  const u16* Ag1 = A + (size_t)(m0 + wave * 16 +  8 + srow) * lda + sperm;
  const u16* Bg0 = B + (size_t)(n0 + wave * 32 +  0 + srow) * K + sperm;
  const u16* Bg1 = B + (size_t)(n0 + wave * 32 +  8 + srow) * K + sperm;
  const u16* Bg2 = B + (size_t)(n0 + wave * 32 + 16 + srow) * K + sperm;
  const u16* Bg3 = B + (size_t)(n0 + wave * 32 + 24 + srow) * K + sperm;
  u16* Al0 = &As[(wave * 16 +  0) * 64];
  u16* Al1 = &As[(wave * 16 +  8) * 64];
  u16* Bl0 = &Bs[(wave * 32 +  0) * 64];
  u16* Bl1 = &Bs[(wave * 32 +  8) * 64];
  u16* Bl2 = &Bs[(wave * 32 + 16) * 64];
  u16* Bl3 = &Bs[(wave * 32 + 24) * 64];

  f32x4 acc[2][4];
#pragma unroll
  for (int i = 0; i < 2; i++)
#pragma unroll
    for (int j = 0; j < 4; j++) { f32x4 z = {0.f,0.f,0.f,0.f}; acc[i][j] = z; }

  const int swz = lrow & 7;

  for (int k0 = 0; k0 < K; k0 += 64) {
    if (k0) __syncthreads();
    g2l16(Ag0 + k0, Al0);
    g2l16(Ag1 + k0, Al1);
    g2l16(Bg0 + k0, Bl0);
    g2l16(Bg1 + k0, Bl1);
    g2l16(Bg2 + k0, Bl2);
    g2l16(Bg3 + k0, Bl3);
    __syncthreads();
#pragma unroll
    for (int s = 0; s < 2; s++) {
      const int c = (s * 4 + quad) ^ swz;
      bf16x8 af[2], bfr[4];
#pragma unroll
      for (int i = 0; i < 2; i++)
        af[i] = *(const bf16x8*)&As[(wr * 32 + i * 16 + lrow) * 64 + c * 8];
#pragma unroll
      for (int j = 0; j < 4; j++)
        bfr[j] = *(const bf16x8*)&Bs[(wc * 64 + j * 16 + lrow) * 64 + c * 8];
#pragma unroll
      for (int i = 0; i < 2; i++)
#pragma unroll
        for (int j = 0; j < 4; j++)
          acc[i][j] = __builtin_amdgcn_mfma_f32_16x16x32_bf16(af[i], bfr[j], acc[i][j], 0, 0, 0);
    }
  }

#pragma unroll
  for (int i = 0; i < 2; i++) {
    const int rowb = m0 + wr * 32 + i * 16 + quad * 4;
#pragma unroll
    for (int j = 0; j < 4; j++) {
      const int col = n0 + wc * 64 + j * 16 + lrow;
      const float bi = bias[col];
#pragma unroll
      for (int r = 0; r < 4; r++)
        outp[(size_t)(rowb + r) * ldo + col] = f2b(acc[i][j][r] + bi);
    }
  }
}

// ---------------- prep ----------------
__global__ void conv_bulk(const float* __restrict__ w1, const float* __restrict__ w2,
                          u16* __restrict__ o1, u16* __restrict__ o2)
{
  const int n4 = (8 * 1024 * 1024) / 4;
  int i = blockIdx.x * 256 + threadIdx.x;
  const float* src; u16* dst;
  if (i < n4) { src = w1; dst = o1; }
  else        { i -= n4; if (i >= n4) return; src = w2; dst = o2; }
  float4 v = ((const float4*)src)[i];
  unsigned p0 = (unsigned)f2b(v.x) | ((unsigned)f2b(v.y) << 16);
  unsigned p1 = (unsigned)f2b(v.z) | ((unsigned)f2b(v.w) << 16);
  uint2 pk; pk.x = p0; pk.y = p1;
  ((uint2*)dst)[i] = pk;
}

// W0 pad(1024x384), Wf pad(384x1024), taA(256x256), taB(256x256), x_bf(8192x384)
__global__ void conv_misc(const float* __restrict__ W0, const float* __restrict__ Wf,
                          const float* __restrict__ ta_in_w, const float* __restrict__ ta_out_w,
                          const float* __restrict__ state, const float* __restrict__ t,
                          u16* __restrict__ w0_bf, u16* __restrict__ wf_bf,
                          u16* __restrict__ taA, u16* __restrict__ taB,
                          u16* __restrict__ x_bf)
{
  int i = blockIdx.x * 256 + threadIdx.x;
  const int nW0 = 1024 * 384;
  const int nWf = 384 * 1024;
  const int nTa = 256 * 256;
  const int nX  = 8192 * 384;
  if (i < nW0) {
    int o = i / 384, k = i - o * 384;
    w0_bf[i] = (k < 270) ? f2b(W0[o * 270 + k]) : (u16)0;
    return;
  }
  i -= nW0;
  if (i < nWf) {
    int n = i >> 10;
    wf_bf[i] = (n < 268) ? f2b(Wf[i]) : (u16)0;
    return;
  }
  i -= nWf;
  if (i < nTa) { taA[i] = f2b(ta_in_w[512 * 256 + i]); return; }
  i -= nTa;
  if (i < nTa) { taB[i] = f2b(ta_out_w[i]); return; }
  i -= nTa;
  if (i < nX) {
    int r = i / 384, c = i - r * 384;
    u16 v;
    if (c < 268) v = f2b(state[r * 268 + c]);
    else if (c == 268) { float ang = t[0] * 0.2617993877991494f; v = f2b(sinf(ang)); }
    else if (c == 269) { float ang = t[0] * 0.2617993877991494f; v = f2b(cosf(ang)); }
    else v = 0;
    x_bf[i] = v;
  }
}

// out += 0.1*delta
__global__ void add_delta(float* __restrict__ out, const u16* __restrict__ eh,
                          const float* __restrict__ state,
                          const float* __restrict__ lp_in_w, const float* __restrict__ lp_in_b,
                          const float* __restrict__ lp_out_w, const float* __restrict__ lp_out_b,
                          const float* __restrict__ loc_proj_w, const float* __restrict__ loc_proj_b,
                          const float* __restrict__ loc_back_w, const float* __restrict__ loc_back_b)
{
  const int idx = blockIdx.x * 256 + threadIdx.x;
  if (idx >= 8192 * 268) return;
  const int row = idx / 268;
  const int col = idx - row * 268;
  if (col < 256) {
    out[idx] += 0.1f * (b2f(eh[row * 256 + col]) - state[idx]);
  } else if (col < 264) {
    const float* srow = state + row * 268 + 256;
    float locp[4], vv[4], dd[4];
#pragma unroll
    for (int e = 0; e < 4; e++) {
      float s = loc_proj_b[e];
#pragma unroll
      for (int z = 0; z < 8; z++) s += loc_proj_w[e * 8 + z] * srow[z];
      locp[e] = s;
    }
#pragma unroll
    for (int e = 0; e < 4; e++) {
      float s = lp_in_b[8 + e];
#pragma unroll
      for (int j = 0; j < 4; j++) s += lp_in_w[(8 + e) * 4 + j] * locp[j];
      vv[e] = s;
    }
#pragma unroll
    for (int e = 0; e < 4; e++) {
      float s = lp_out_b[e];
#pragma unroll
      for (int j = 0; j < 4; j++) s += lp_out_w[e * 4 + j] * vv[j];
      dd[e] = s - locp[e];
    }
    const int z = col - 256;
    float s = loc_back_b[z];
#pragma unroll
    for (int e = 0; e < 4; e++) s += loc_back_w[z * 4 + e] * dd[e];
    out[idx] += 0.1f * s;
  }
}

extern "C" void kernel_launch(void* const* d_in, const int* in_sizes, int n_in,
                              void* d_out, int out_size, void* d_ws, size_t ws_size,
                              hipStream_t stream)
{
  const float* t          = (const float*)d_in[0];
  const float* state      = (const float*)d_in[1];
  const float* W0         = (const float*)d_in[2];
  const float* b0         = (const float*)d_in[3];
  const float* rW1        = (const float*)d_in[4];
  const float* rb1        = (const float*)d_in[5];
  const float* rW2        = (const float*)d_in[6];
  const float* rb2        = (const float*)d_in[7];
  const float* Wf         = (const float*)d_in[8];
  const float* bfv        = (const float*)d_in[9];
  const float* lp_in_w    = (const float*)d_in[10];
  const float* lp_in_b    = (const float*)d_in[11];
  const float* lp_out_w   = (const float*)d_in[12];
  const float* lp_out_b   = (const float*)d_in[13];
  const float* ta_in_w    = (const float*)d_in[14];
  const float* ta_in_b    = (const float*)d_in[15];
  const float* ta_out_w   = (const float*)d_in[16];
  const float* ta_out_b   = (const float*)d_in[17];
  const float* loc_proj_w = (const float*)d_in[18];
  const float* loc_proj_b = (const float*)d_in[19];
  const float* loc_back_w = (const float*)d_in[20];
  const float* loc_back_b = (const float*)d_in[21];
  float* out = (float*)d_out;

  char* ws = (char*)d_ws;
  auto alloc = [&](size_t bytes) { char* p = ws; ws += (bytes + 255) & ~(size_t)255; return p; };
  u16* rw1_bf = (u16*)alloc((size_t)8 * 1024 * 1024 * 2);
  u16* rw2_bf = (u16*)alloc((size_t)8 * 1024 * 1024 * 2);
  u16* w0_bf  = (u16*)alloc((size_t)1024 * 384 * 2);
  u16* wf_bf  = (u16*)alloc((size_t)384 * 1024 * 2);
  u16* taA_bf = (u16*)alloc((size_t)256 * 256 * 2);
  u16* taB_bf = (u16*)alloc((size_t)256 * 256 * 2);
  u16* x_bf   = (u16*)alloc((size_t)8192 * 384 * 2);
  u16* h_bf   = (u16*)alloc((size_t)8192 * 1024 * 2);
  u16* tmp_bf = (u16*)alloc((size_t)8192 * 1024 * 2);
  u16* v2_bf  = (u16*)alloc((size_t)8192 * 256 * 2);
  u16* eh_bf  = (u16*)alloc((size_t)8192 * 256 * 2);

  conv_bulk<<<16384, 256, 0, stream>>>(rW1, rW2, rw1_bf, rw2_bf);
  conv_misc<<<15872, 256, 0, stream>>>(W0, Wf, ta_in_w, ta_out_w, state, t,
                                       w0_bf, wf_bf, taA_bf, taB_bf, x_bf);

  // h = relu(x @ W0^T + b0)   K padded 270->384
  pgemm<0, 384, 384><<<dim3(8, 64), 256, 0, stream>>>(x_bf, w0_bf, b0, nullptr, h_bf, 1024, 1024);

  // 8 residual blocks
  for (int r = 0; r < 8; r++) {
    pgemm<1, 1024, 1024><<<dim3(8, 64), 256, 0, stream>>>(
        h_bf, rw1_bf + ((size_t)r << 20), rb1 + (r << 10), nullptr, tmp_bf, 1024, 1024);
    pgemm<2, 1024, 1024><<<dim3(8, 64), 256, 0, stream>>>(
        tmp_bf, rw2_bf + ((size_t)r << 20), rb2 + (r << 10), h_bf, h_bf, 1024, 1024);
  }

  // ta path: v2 = x[:, :256] @ taA^T + b ; eh = v2 @ taB^T + b
  gemm_bt<<<dim3(2, 128), 256, 0, stream>>>(x_bf, taA_bf, ta_in_b + 512, v2_bf, 256, 384, 256);
  gemm_bt<<<dim3(2, 128), 256, 0, stream>>>(v2_bf, taB_bf, ta_out_b, eh_bf, 256, 256, 256);

  // core = h @ Wf^T + bf -> f32 out (N padded 268->384)
  pgemm<3, 1024, 1024><<<dim3(3, 64), 256, 0, stream>>>(h_bf, wf_bf, bfv, nullptr, out, 268, 268);

  // out += 0.1*delta
  add_delta<<<8576, 256, 0, stream>>>(out, eh_bf, state,
                                      lp_in_w, lp_in_b, lp_out_w, lp_out_b,
                                      loc_proj_w, loc_proj_b, loc_back_w, loc_back_b);
}

// Round 6
// 589.630 us; speedup vs baseline: 2.5844x; 1.1830x over previous
//
#include <hip/hip_runtime.h>
#include <hip/hip_bf16.h>

// OldODEFunc: B=8192, S=268, H=1024, R=8, A=256, E=4, Z=8, P=4.
// R6: 128x128 tile, BK=128 phases, 512-thread blocks (8 waves, wave-tile
// 32x64) -> 4 waves/SIMD latency hiding. Grid (m=64, n=8): XCD = m%8 ->
// per-XCD A-slice (2.1 MB) L2-resident, read once from HBM.

typedef unsigned short u16;
typedef __bf16 bf16x8 __attribute__((ext_vector_type(8)));
typedef float f32x4 __attribute__((ext_vector_type(4)));

__device__ __forceinline__ u16 f2b(float f) {
  union { float f; unsigned u; } v; v.f = f;
  unsigned r = v.u + 0x7FFFu + ((v.u >> 16) & 1u);   // RNE
  return (u16)(r >> 16);
}
__device__ __forceinline__ float b2f(u16 s) {
  union { unsigned u; float f; } v; v.u = ((unsigned)s) << 16;
  return v.f;
}

// async global->LDS, 16B per lane; lds dest = wave-uniform base + lane*16
__device__ __forceinline__ void g2l16(const u16* g, u16* l) {
  __builtin_amdgcn_global_load_lds(
      (__attribute__((address_space(1))) void*)g,
      (__attribute__((address_space(3))) void*)l, 16, 0, 0);
}

// ---------------- main GEMM ----------------
// C(128M x 128N) = A(128 x KK, row-major, LDA) @ W(N x KK)^T.
// LDS: As/Bs 128x128 bf16 (32 KB each), rows of 16 8-elem chunks,
// chunk swizzle: logical c at phys c ^ (row & 7).
// 8 waves, 4x2 over the tile: wave-tile 32M x 64N, acc[2][4].
// Phase = BK 128: 8 g2l16/wave, one drain, 4 substeps x 8 MFMA/wave.
// MODE 0: relu->bf16  1: tanh->bf16  2: tanh(+resid in-place)->bf16
// MODE 3: f32 out, cols<nreal
template<int MODE, int KK, int LDA>
__global__ __launch_bounds__(512, 4)
void pgemm(const u16* __restrict__ A, const u16* __restrict__ W,
           const float* __restrict__ bias, const u16* __restrict__ resid,
           void* __restrict__ outp, int nreal, int ldo)
{
  __shared__ __align__(16) u16 As[128 * 128];   // 32 KB
  __shared__ __align__(16) u16 Bs[128 * 128];   // 32 KB
  const int tid  = threadIdx.x;
  const int wave = tid >> 6;
  const int lane = tid & 63;
  const int m0 = blockIdx.x << 7;   // grid.x = m -> XCD = m%8 (A-affinity)
  const int n0 = blockIdx.y << 7;
  const int wr = wave >> 1, wc = wave & 1;       // 4x2 waves, 32M x 64N each
  const int lrow = lane & 15, quad = lane >> 4;
  const int sw = lrow & 7;

  // staging: each inst covers 4 rows x 128 elems (64 lanes x 16B).
  const int srow4  = lane >> 4;        // 0..3: row within 4-row group
  const int schunk = lane & 15;        // phys chunk within row
  const int ce = (schunk ^ srow4) << 3;         // g even: row&7 = srow4
  const int co = (schunk ^ (srow4 + 4)) << 3;   // g odd:  row&7 = srow4+4

  const u16* aE = A + (size_t)(m0 + wave * 16 + srow4) * LDA + ce;
  const u16* aO = A + (size_t)(m0 + wave * 16 + srow4) * LDA + co;
  const u16* bE = W + (size_t)(n0 + wave * 16 + srow4) * KK + ce;
  const u16* bO = W + (size_t)(n0 + wave * 16 + srow4) * KK + co;
  u16* AsW = &As[(wave * 16) * 128];
  u16* BsW = &Bs[(wave * 16) * 128];

  f32x4 acc[2][4];
#pragma unroll
  for (int i = 0; i < 2; i++)
#pragma unroll
    for (int j = 0; j < 4; j++) { f32x4 z = {0.f,0.f,0.f,0.f}; acc[i][j] = z; }

  for (int p = 0; p < KK / 128; p++) {
    if (p) __syncthreads();            // prior phase reads done
    const int ko = p << 7;
#pragma unroll
    for (int g = 0; g < 4; g++)
      g2l16(((g & 1) ? aO : aE) + g * 4 * LDA + ko, AsW + g * 4 * 128);
#pragma unroll
    for (int g = 0; g < 4; g++)
      g2l16(((g & 1) ? bO : bE) + g * 4 * KK + ko, BsW + g * 4 * 128);
    __syncthreads();                   // drain: staging visible
#pragma unroll
    for (int s = 0; s < 4; s++) {
      const int phys = (s * 4 + quad) ^ sw;
      bf16x8 af[2], bfr[4];
#pragma unroll
      for (int i = 0; i < 2; i++) {
        const int ra = wr * 32 + i * 16 + lrow;
        af[i] = *(const bf16x8*)&As[(ra * 16 + phys) * 8];
      }
#pragma unroll
      for (int j = 0; j < 4; j++) {
        const int rb = wc * 64 + j * 16 + lrow;
        bfr[j] = *(const bf16x8*)&Bs[(rb * 16 + phys) * 8];
      }
#pragma unroll
      for (int i = 0; i < 2; i++)
#pragma unroll
        for (int j = 0; j < 4; j++)
          acc[i][j] = __builtin_amdgcn_mfma_f32_16x16x32_bf16(af[i], bfr[j], acc[i][j], 0, 0, 0);
    }
  }

  auto th = [](float x) {
    x = fminf(fmaxf(x, -40.f), 40.f);
    float a = __builtin_amdgcn_exp2f(2.88539008177793f * x);
    return (a - 1.f) * __builtin_amdgcn_rcpf(a + 1.f);
  };

  // epilogue: C/D layout col = lane&15, row = quad*4 + reg
#pragma unroll
  for (int i = 0; i < 2; i++) {
    const int rowb = m0 + wr * 32 + i * 16 + quad * 4;
#pragma unroll
    for (int j = 0; j < 4; j++) {
      const int col = n0 + wc * 64 + j * 16 + lrow;
      const float bi = (col < nreal) ? bias[col] : 0.f;
#pragma unroll
      for (int r = 0; r < 4; r++) {
        const int row = rowb + r;
        float v = acc[i][j][r] + bi;
        if (MODE == 0) {
          v = v > 0.f ? v : 0.f;
          ((u16*)outp)[(size_t)row * ldo + col] = f2b(v);
        } else if (MODE == 1) {
          ((u16*)outp)[(size_t)row * ldo + col] = f2b(th(v));
        } else if (MODE == 2) {
          v += b2f(resid[(size_t)row * ldo + col]);
          ((u16*)outp)[(size_t)row * ldo + col] = f2b(th(v));
        } else if (MODE == 3) {
          if (col < nreal) ((float*)outp)[(size_t)row * ldo + col] = v;
        }
      }
    }
  }
}

// ---------------- small GEMM for ta path ----------------
// 64M x 128N tile, BK=64, LDS-staged, xor swizzle, plain bf16 out.
__global__ __launch_bounds__(256, 4)
void gemm_bt(const u16* __restrict__ A, const u16* __restrict__ B,
             const float* __restrict__ bias, u16* __restrict__ outp,
             int K, int lda, int ldo)
{
  __shared__ __align__(16) u16 As[64 * 64];
  __shared__ __align__(16) u16 Bs[128 * 64];
  const int tid  = threadIdx.x;
  const int wave = tid >> 6;
  const int lane = tid & 63;
  const int m0 = blockIdx.y << 6;
  const int n0 = blockIdx.x << 7;
  const int wr = wave >> 1, wc = wave & 1;
  const int lrow = lane & 15, quad = lane >> 4;
  const int srow  = lane >> 3;
  const int sperm = ((lane & 7) ^ (srow & 7)) << 3;

  const u16* Ag0 = A + (size_t)(m0 + wave * 16 +  0 + srow) * lda + sperm;
  const u16* Ag1 = A + (size_t)(m0 + wave * 16 +  8 + srow) * lda + sperm;
  const u16* Bg0 = B + (size_t)(n0 + wave * 32 +  0 + srow) * K + sperm;
  const u16* Bg1 = B + (size_t)(n0 + wave * 32 +  8 + srow) * K + sperm;
  const u16* Bg2 = B + (size_t)(n0 + wave * 32 + 16 + srow) * K + sperm;
  const u16* Bg3 = B + (size_t)(n0 + wave * 32 + 24 + srow) * K + sperm;
  u16* Al0 = &As[(wave * 16 +  0) * 64];
  u16* Al1 = &As[(wave * 16 +  8) * 64];
  u16* Bl0 = &Bs[(wave * 32 +  0) * 64];
  u16* Bl1 = &Bs[(wave * 32 +  8) * 64];
  u16* Bl2 = &Bs[(wave * 32 + 16) * 64];
  u16* Bl3 = &Bs[(wave * 32 + 24) * 64];

  f32x4 acc[2][4];
#pragma unroll
  for (int i = 0; i < 2; i++)
#pragma unroll
    for (int j = 0; j < 4; j++) { f32x4 z = {0.f,0.f,0.f,0.f}; acc[i][j] = z; }

  const int swz = lrow & 7;

  for (int k0 = 0; k0 < K; k0 += 64) {
    if (k0) __syncthreads();
    g2l16(Ag0 + k0, Al0);
    g2l16(Ag1 + k0, Al1);
    g2l16(Bg0 + k0, Bl0);
    g2l16(Bg1 + k0, Bl1);
    g2l16(Bg2 + k0, Bl2);
    g2l16(Bg3 + k0, Bl3);
    __syncthreads();
#pragma unroll
    for (int s = 0; s < 2; s++) {
      const int c = (s * 4 + quad) ^ swz;
      bf16x8 af[2], bfr[4];
#pragma unroll
      for (int i = 0; i < 2; i++)
        af[i] = *(const bf16x8*)&As[(wr * 32 + i * 16 + lrow) * 64 + c * 8];
#pragma unroll
      for (int j = 0; j < 4; j++)
        bfr[j] = *(const bf16x8*)&Bs[(wc * 64 + j * 16 + lrow) * 64 + c * 8];
#pragma unroll
      for (int i = 0; i < 2; i++)
#pragma unroll
        for (int j = 0; j < 4; j++)
          acc[i][j] = __builtin_amdgcn_mfma_f32_16x16x32_bf16(af[i], bfr[j], acc[i][j], 0, 0, 0);
    }
  }

#pragma unroll
  for (int i = 0; i < 2; i++) {
    const int rowb = m0 + wr * 32 + i * 16 + quad * 4;
#pragma unroll
    for (int j = 0; j < 4; j++) {
      const int col = n0 + wc * 64 + j * 16 + lrow;
      const float bi = bias[col];
#pragma unroll
      for (int r = 0; r < 4; r++)
        outp[(size_t)(rowb + r) * ldo + col] = f2b(acc[i][j][r] + bi);
    }
  }
}

// ---------------- prep ----------------
__global__ void conv_bulk(const float* __restrict__ w1, const float* __restrict__ w2,
                          u16* __restrict__ o1, u16* __restrict__ o2)
{
  const int n4 = (8 * 1024 * 1024) / 4;
  int i = blockIdx.x * 256 + threadIdx.x;
  const float* src; u16* dst;
  if (i < n4) { src = w1; dst = o1; }
  else        { i -= n4; if (i >= n4) return; src = w2; dst = o2; }
  float4 v = ((const float4*)src)[i];
  unsigned p0 = (unsigned)f2b(v.x) | ((unsigned)f2b(v.y) << 16);
  unsigned p1 = (unsigned)f2b(v.z) | ((unsigned)f2b(v.w) << 16);
  uint2 pk; pk.x = p0; pk.y = p1;
  ((uint2*)dst)[i] = pk;
}

// W0 pad(1024x384), Wf pad(384x1024), taA(256x256), taB(256x256), x_bf(8192x384)
__global__ void conv_misc(const float* __restrict__ W0, const float* __restrict__ Wf,
                          const float* __restrict__ ta_in_w, const float* __restrict__ ta_out_w,
                          const float* __restrict__ state, const float* __restrict__ t,
                          u16* __restrict__ w0_bf, u16* __restrict__ wf_bf,
                          u16* __restrict__ taA, u16* __restrict__ taB,
                          u16* __restrict__ x_bf)
{
  int i = blockIdx.x * 256 + threadIdx.x;
  const int nW0 = 1024 * 384;
  const int nWf = 384 * 1024;
  const int nTa = 256 * 256;
  const int nX  = 8192 * 384;
  if (i < nW0) {
    int o = i / 384, k = i - o * 384;
    w0_bf[i] = (k < 270) ? f2b(W0[o * 270 + k]) : (u16)0;
    return;
  }
  i -= nW0;
  if (i < nWf) {
    int n = i >> 10;
    wf_bf[i] = (n < 268) ? f2b(Wf[i]) : (u16)0;
    return;
  }
  i -= nWf;
  if (i < nTa) { taA[i] = f2b(ta_in_w[512 * 256 + i]); return; }
  i -= nTa;
  if (i < nTa) { taB[i] = f2b(ta_out_w[i]); return; }
  i -= nTa;
  if (i < nX) {
    int r = i / 384, c = i - r * 384;
    u16 v;
    if (c < 268) v = f2b(state[r * 268 + c]);
    else if (c == 268) { float ang = t[0] * 0.2617993877991494f; v = f2b(sinf(ang)); }
    else if (c == 269) { float ang = t[0] * 0.2617993877991494f; v = f2b(cosf(ang)); }
    else v = 0;
    x_bf[i] = v;
  }
}

// out += 0.1*delta
__global__ void add_delta(float* __restrict__ out, const u16* __restrict__ eh,
                          const float* __restrict__ state,
                          const float* __restrict__ lp_in_w, const float* __restrict__ lp_in_b,
                          const float* __restrict__ lp_out_w, const float* __restrict__ lp_out_b,
                          const float* __restrict__ loc_proj_w, const float* __restrict__ loc_proj_b,
                          const float* __restrict__ loc_back_w, const float* __restrict__ loc_back_b)
{
  const int idx = blockIdx.x * 256 + threadIdx.x;
  if (idx >= 8192 * 268) return;
  const int row = idx / 268;
  const int col = idx - row * 268;
  if (col < 256) {
    out[idx] += 0.1f * (b2f(eh[row * 256 + col]) - state[idx]);
  } else if (col < 264) {
    const float* srow = state + row * 268 + 256;
    float locp[4], vv[4], dd[4];
#pragma unroll
    for (int e = 0; e < 4; e++) {
      float s = loc_proj_b[e];
#pragma unroll
      for (int z = 0; z < 8; z++) s += loc_proj_w[e * 8 + z] * srow[z];
      locp[e] = s;
    }
#pragma unroll
    for (int e = 0; e < 4; e++) {
      float s = lp_in_b[8 + e];
#pragma unroll
      for (int j = 0; j < 4; j++) s += lp_in_w[(8 + e) * 4 + j] * locp[j];
      vv[e] = s;
    }
#pragma unroll
    for (int e = 0; e < 4; e++) {
      float s = lp_out_b[e];
#pragma unroll
      for (int j = 0; j < 4; j++) s += lp_out_w[e * 4 + j] * vv[j];
      dd[e] = s - locp[e];
    }
    const int z = col - 256;
    float s = loc_back_b[z];
#pragma unroll
    for (int e = 0; e < 4; e++) s += loc_back_w[z * 4 + e] * dd[e];
    out[idx] += 0.1f * s;
  }
}

extern "C" void kernel_launch(void* const* d_in, const int* in_sizes, int n_in,
                              void* d_out, int out_size, void* d_ws, size_t ws_size,
                              hipStream_t stream)
{
  const float* t          = (const float*)d_in[0];
  const float* state      = (const float*)d_in[1];
  const float* W0         = (const float*)d_in[2];
  const float* b0         = (const float*)d_in[3];
  const float* rW1        = (const float*)d_in[4];
  const float* rb1        = (const float*)d_in[5];
  const float* rW2        = (const float*)d_in[6];
  const float* rb2        = (const float*)d_in[7];
  const float* Wf         = (const float*)d_in[8];
  const float* bfv        = (const float*)d_in[9];
  const float* lp_in_w    = (const float*)d_in[10];
  const float* lp_in_b    = (const float*)d_in[11];
  const float* lp_out_w   = (const float*)d_in[12];
  const float* lp_out_b   = (const float*)d_in[13];
  const float* ta_in_w    = (const float*)d_in[14];
  const float* ta_in_b    = (const float*)d_in[15];
  const float* ta_out_w   = (const float*)d_in[16];
  const float* ta_out_b   = (const float*)d_in[17];
  const float* loc_proj_w = (const float*)d_in[18];
  const float* loc_proj_b = (const float*)d_in[19];
  const float* loc_back_w = (const float*)d_in[20];
  const float* loc_back_b = (const float*)d_in[21];
  float* out = (float*)d_out;

  char* ws = (char*)d_ws;
  auto alloc = [&](size_t bytes) { char* p = ws; ws += (bytes + 255) & ~(size_t)255; return p; };
  u16* rw1_bf = (u16*)alloc((size_t)8 * 1024 * 1024 * 2);
  u16* rw2_bf = (u16*)alloc((size_t)8 * 1024 * 1024 * 2);
  u16* w0_bf  = (u16*)alloc((size_t)1024 * 384 * 2);
  u16* wf_bf  = (u16*)alloc((size_t)384 * 1024 * 2);
  u16* taA_bf = (u16*)alloc((size_t)256 * 256 * 2);
  u16* taB_bf = (u16*)alloc((size_t)256 * 256 * 2);
  u16* x_bf   = (u16*)alloc((size_t)8192 * 384 * 2);
  u16* h_bf   = (u16*)alloc((size_t)8192 * 1024 * 2);
  u16* tmp_bf = (u16*)alloc((size_t)8192 * 1024 * 2);
  u16* v2_bf  = (u16*)alloc((size_t)8192 * 256 * 2);
  u16* eh_bf  = (u16*)alloc((size_t)8192 * 256 * 2);

  conv_bulk<<<16384, 256, 0, stream>>>(rW1, rW2, rw1_bf, rw2_bf);
  conv_misc<<<15872, 256, 0, stream>>>(W0, Wf, ta_in_w, ta_out_w, state, t,
                                       w0_bf, wf_bf, taA_bf, taB_bf, x_bf);

  // h = relu(x @ W0^T + b0)   K padded 270->384
  pgemm<0, 384, 384><<<dim3(64, 8), 512, 0, stream>>>(x_bf, w0_bf, b0, nullptr, h_bf, 1024, 1024);

  // 8 residual blocks
  for (int r = 0; r < 8; r++) {
    pgemm<1, 1024, 1024><<<dim3(64, 8), 512, 0, stream>>>(
        h_bf, rw1_bf + ((size_t)r << 20), rb1 + (r << 10), nullptr, tmp_bf, 1024, 1024);
    pgemm<2, 1024, 1024><<<dim3(64, 8), 512, 0, stream>>>(
        tmp_bf, rw2_bf + ((size_t)r << 20), rb2 + (r << 10), h_bf, h_bf, 1024, 1024);
  }

  // ta path: v2 = x[:, :256] @ taA^T + b ; eh = v2 @ taB^T + b
  gemm_bt<<<dim3(2, 128), 256, 0, stream>>>(x_bf, taA_bf, ta_in_b + 512, v2_bf, 256, 384, 256);
  gemm_bt<<<dim3(2, 128), 256, 0, stream>>>(v2_bf, taB_bf, ta_out_b, eh_bf, 256, 256, 256);

  // core = h @ Wf^T + bf -> f32 out (N padded 268->384)
  pgemm<3, 1024, 1024><<<dim3(64, 3), 512, 0, stream>>>(h_bf, wf_bf, bfv, nullptr, out, 268, 268);

  // out += 0.1*delta
  add_delta<<<8576, 256, 0, stream>>>(out, eh_bf, state,
                                      lp_in_w, lp_in_b, lp_out_w, lp_out_b,
                                      loc_proj_w, loc_proj_b, loc_back_w, loc_back_b);
}